// Round 6
// baseline (261.259 us; speedup 1.0000x reference)
//
#include <hip/hip_runtime.h>

#define LPC_N 32
#define LPC_EPS 1e-5f
#define NREG 14                       // lags 0..13: f2 register-resident
#define NLDS (LPC_N + 1 - NREG)       // lags 14..32: per-wave LDS (19 lags)

typedef float f2 __attribute__((ext_vector_type(2)));

__device__ __forceinline__ f2 rcp2(f2 v) {
    f2 r;
    r.x = __builtin_amdgcn_rcpf(v.x);
    r.y = __builtin_amdgcn_rcpf(v.y);
    return r;
}

// R0-R4 synthesis (R5 was an infra failure, not a kernel failure):
//  - R0 (f2, 2 frames/thread) proved packed math HALVES VALU issue time
//    (17 us vs 32 us) but died at 27% occupancy (130-reg working set).
//  - R1/R3/R4 (scalar) proved the scalar structure is latency-boxed at
//    90 us: VGPR_Count pinned at 36 (allocator shadows arrays in the
//    unified file under any cap), and ac+lp storage per frame caps
//    residency at ~60% for ANY scalar layout.
// This round: f2 math + LDS split, sized so regs (cap 128, honest ~114)
// and LDS (38.9 KB/block -> 4 blocks/CU) BOTH bind at 16 waves/CU (50%):
// double R0's occupancy at R0's halved issue rate.
//  - lp[32] f2 (64 regs) + ac[0..13] f2 (28 regs) + temps ~20 = ~114.
//  - lags 14..32 in per-wave LDS as f2: [lag][lane] layout, each lane
//    touches only its own column (no barrier); ds_read_b64 on the DS pipe.
__global__ __launch_bounds__(256, 4) void levinson_kernel(
    const float* __restrict__ pAC,   // [N+1, T]
    float* __restrict__ out,         // [N, T]
    int T)
{
    __shared__ f2 smem[4 * NLDS * 64];   // 38912 B/block, per-wave chunks

    const int tid  = threadIdx.x;
    const int lane = tid & 63;
    const int wv   = tid >> 6;
    const int p    = blockIdx.x * blockDim.x + tid;   // frame-pair index
    const int TP   = T >> 1;
    if (p >= TP) return;

    f2* wbuf = smem + wv * (NLDS * 64);

    // Stage cold lags into per-wave LDS (coalesced dwordx2 loads, 8 B/lane).
    // Direct global->reg->LDS per lag, no staging array: minimal live temps.
#pragma unroll
    for (int k = 0; k < NLDS; ++k) {
        f2 v = *(const f2*)(pAC + (size_t)(NREG + k) * T + 2 * (size_t)p);
        wbuf[k * 64 + lane] = v;
    }

    // Hot lags -> registers.
    f2 ac[NREG];
#pragma unroll
    for (int k = 0; k < NREG; ++k)
        ac[k] = *(const f2*)(pAC + (size_t)k * T + 2 * (size_t)p);

    // Fully unrolled => m is compile-time: folds to a VGPR pair read or a
    // ds_read_b64 with an immediate offset.
    auto AC = [&](int m) -> f2 {
        return (m < NREG) ? ac[m] : wbuf[(m - NREG) * 64 + lane];
    };

    f2 lp[LPC_N];
    f2 E = ac[0];

#pragma unroll
    for (int i = 0; i < LPC_N; ++i) {
        // rcp issued first: latency hides under the dot product.
        f2 invE = rcp2(E);

        // acc = ac[i+1] + sum_{j<i} lp[j]*ac[i-j], two independent FMA chains.
        f2 s0 = AC(i + 1);
        f2 s1 = {0.0f, 0.0f};
#pragma unroll
        for (int j = 0; j + 1 < i; j += 2) {
            s0 += lp[j]     * AC(i - j);
            s1 += lp[j + 1] * AC(i - j - 1);
        }
        if (i & 1) {                    // leftover j = i-1 when i is odd
            s0 += lp[i - 1] * ac[1];
        }
        f2 acc = s0 + s1;

        f2 ki = acc * invE;
        f2 c  = {1.0f, 1.0f};
        c -= ki * ki;
        c.x = fmaxf(c.x, LPC_EPS);
        c.y = fmaxf(c.y, LPC_EPS);
        E *= c;

        // lp[j] = lp[j] - ki*lp[i-1-j] from OLD lp: pairwise swap update.
#pragma unroll
        for (int j = 0; j < i - 1 - j; ++j) {
            f2 a = lp[j];
            f2 b = lp[i - 1 - j];
            lp[j]         = a - ki * b;
            lp[i - 1 - j] = b - ki * a;
        }
        if (i & 1) {
            int m = (i - 1) >> 1;       // self-paired middle element
            lp[m] = lp[m] - ki * lp[m];
        }
        lp[i] = -ki;
    }

    // Nontemporal coalesced dwordx2 stores: write-once/never-read.
#pragma unroll
    for (int i = 0; i < LPC_N; ++i) {
        __builtin_nontemporal_store(lp[i], (f2*)(out + (size_t)i * T + 2 * (size_t)p));
    }
}

extern "C" void kernel_launch(void* const* d_in, const int* in_sizes, int n_in,
                              void* d_out, int out_size, void* d_ws, size_t ws_size,
                              hipStream_t stream)
{
    const float* pAC = (const float*)d_in[0];
    float* out = (float*)d_out;
    int T = in_sizes[0] / (LPC_N + 1);   // 1048576

    int TP = T >> 1;                     // 524288 frame pairs
    int block = 256;
    int grid = (TP + block - 1) / block; // 2048 blocks
    levinson_kernel<<<grid, block, 0, stream>>>(pAC, out, T);
}

// Round 7
// 244.154 us; speedup vs baseline: 1.0701x; 1.0701x over previous
//
#include <hip/hip_runtime.h>

#define LPC_N 32
#define LPC_EPS 1e-5f
#define PF 9      // software-prefetch depth: prologue loads ac[0..8]

// R1/R3/R4 invariant: VGPR=36 + occ ~5 waves/SIMD + VALU-busy 32us + dur 90us
// = load-all-33-then-drain structure. The AGPR shadow (unified-RF parking of
// the ac/lp arrays) forces every v_accvgpr_write to wait for its load, so the
// whole batch drains before iteration 0 and the wave's life is serial
// [drain][compute][store] -- both pipes idle ~64% of the time.
// Fix (never tried in R0-R6): stream the lags IN-LOOP. Iteration i is the
// first consumer of ac[i+1], so load ac[i+PF] inside iteration i. Loads
// issue & complete in order -> each AGPR park waits a COUNTED vmcnt, HBM
// traffic spreads across the whole recursion, no top drain. Math, state,
// and occupancy are identical to the 90us baseline; only load placement
// changes. No launch_bounds min-wave request (R2/R4/R6: caps => spills).
__global__ __launch_bounds__(256) void levinson_kernel(
    const float* __restrict__ pAC,   // [N+1, T]
    float* __restrict__ out,         // [N, T]
    int T)
{
    int t = blockIdx.x * blockDim.x + threadIdx.x;   // frame index
    if (t >= T) return;

    float ac[LPC_N + 1];
#pragma unroll
    for (int k = 0; k < PF; ++k)                     // prologue: 9 loads
        ac[k] = pAC[(size_t)k * T + t];

    float lp[LPC_N];
    float E = ac[0];

#pragma unroll
    for (int i = 0; i < LPC_N; ++i) {
        // Stream one lag per iteration, PF-1=8 iterations ahead of first use.
        if (i + PF <= LPC_N)
            ac[i + PF] = pAC[(size_t)(i + PF) * T + t];

        // rcp issued first: latency hides under the dot product.
        float invE = __builtin_amdgcn_rcpf(E);

        // acc = ac[i+1] + sum_{j<i} lp[j]*ac[i-j], two independent FMA chains.
        float s0 = ac[i + 1];
        float s1 = 0.0f;
#pragma unroll
        for (int j = 0; j + 1 < i; j += 2) {
            s0 += lp[j]     * ac[i - j];
            s1 += lp[j + 1] * ac[i - j - 1];
        }
        if (i & 1) {                    // leftover j = i-1 when i is odd
            s0 += lp[i - 1] * ac[1];
        }
        float acc = s0 + s1;

        float ki = acc * invE;
        float c  = fmaxf(1.0f - ki * ki, LPC_EPS);
        E *= c;

        // lp[j] = lp[j] - ki*lp[i-1-j] from OLD lp: pairwise swap update.
#pragma unroll
        for (int j = 0; j < i - 1 - j; ++j) {
            float a = lp[j];
            float b = lp[i - 1 - j];
            lp[j]         = a - ki * b;
            lp[i - 1 - j] = b - ki * a;
        }
        if (i & 1) {
            int m = (i - 1) >> 1;       // self-paired middle element
            lp[m] = lp[m] - ki * lp[m];
        }
        lp[i] = -ki;
    }

    // Nontemporal coalesced stores: write-once/never-read, keep out of LLC.
#pragma unroll
    for (int i = 0; i < LPC_N; ++i) {
        __builtin_nontemporal_store(lp[i], &out[(size_t)i * T + t]);
    }
}

extern "C" void kernel_launch(void* const* d_in, const int* in_sizes, int n_in,
                              void* d_out, int out_size, void* d_ws, size_t ws_size,
                              hipStream_t stream)
{
    const float* pAC = (const float*)d_in[0];
    float* out = (float*)d_out;
    int T = in_sizes[0] / (LPC_N + 1);   // 1048576

    int block = 256;
    int grid = (T + block - 1) / block;  // 4096 blocks
    levinson_kernel<<<grid, block, 0, stream>>>(pAC, out, T);
}